// Round 3
// baseline (1503.864 us; speedup 1.0000x reference)
//
#include <hip/hip_runtime.h>

#define H 128
#define FN 16
#define FE 8
#define NBUK_MAX 1600   // buckets = ceil(N/64) = 1563 for N=100k

// ============================ bucketed counting sort ============================
// Pass 1: bin edges by key>>6 into contiguous bucket regions.
// Pass 2: per-bucket counting sort over the 64-key sub-range; emits offs[].

__global__ __launch_bounds__(256) void k_p1_hist(
    const int* __restrict__ key, int* __restrict__ bcnt, int E, int nbuk) {
  __shared__ int h[NBUK_MAX];
  for (int i = threadIdx.x; i < nbuk; i += 256) h[i] = 0;
  __syncthreads();
  for (int e = blockIdx.x * 256 + threadIdx.x; e < E; e += gridDim.x * 256)
    atomicAdd(&h[key[e] >> 6], 1);
  __syncthreads();
  for (int i = threadIdx.x; i < nbuk; i += 256) {
    int v = h[i];
    if (v) atomicAdd(&bcnt[i], v);
  }
}

// scan over nbuk values (3-kernel scan, reused from round 2)
__global__ __launch_bounds__(256) void k_scan1(
    const int* __restrict__ cnt, int* __restrict__ bsum, int N) {
  __shared__ int s[256];
  int base = blockIdx.x * 1024 + threadIdx.x * 4;
  int t = 0;
#pragma unroll
  for (int j = 0; j < 4; j++) { int i = base + j; if (i < N) t += cnt[i]; }
  s[threadIdx.x] = t; __syncthreads();
  for (int off = 128; off > 0; off >>= 1) {
    if (threadIdx.x < off) s[threadIdx.x] += s[threadIdx.x + off];
    __syncthreads();
  }
  if (threadIdx.x == 0) bsum[blockIdx.x] = s[0];
}

__global__ __launch_bounds__(128) void k_scan2(
    const int* __restrict__ bsum, int* __restrict__ bsumEx,
    int* __restrict__ offs, int NB, int N) {
  __shared__ int s[128];
  int tid = threadIdx.x;
  int v = (tid < NB) ? bsum[tid] : 0;
  s[tid] = v; __syncthreads();
  for (int off = 1; off < 128; off <<= 1) {
    int t = 0;
    if (tid >= off) t = s[tid - off];
    __syncthreads();
    if (tid >= off) s[tid] += t;
    __syncthreads();
  }
  if (tid < NB) bsumEx[tid] = s[tid] - v;
  if (tid == 127) offs[N] = s[127];
}

__global__ __launch_bounds__(256) void k_scan3(
    const int* __restrict__ cnt, const int* __restrict__ bsumEx,
    int* __restrict__ offs, int N) {
  __shared__ int s[256];
  int tid = threadIdx.x;
  int base = blockIdx.x * 1024 + tid * 4;
  int c[4]; int t = 0;
#pragma unroll
  for (int j = 0; j < 4; j++) { int i = base + j; c[j] = (i < N) ? cnt[i] : 0; t += c[j]; }
  s[tid] = t; __syncthreads();
  for (int off = 1; off < 256; off <<= 1) {
    int u = 0;
    if (tid >= off) u = s[tid - off];
    __syncthreads();
    if (tid >= off) s[tid] += u;
    __syncthreads();
  }
  int ex = s[tid] - t + bsumEx[blockIdx.x];
#pragma unroll
  for (int j = 0; j < 4; j++) {
    int i = base + j;
    if (i < N) offs[i] = ex;
    ex += c[j];
  }
}

// pass-1 scatter: block handles a chunk of 8192 edges; LDS hist -> one global
// cursor reservation per (block,bucket) -> coalesced contiguous writes.
__global__ __launch_bounds__(256) void k_p1_scatter(
    const int* __restrict__ key, const int* __restrict__ dsts,
    const float* __restrict__ vals, int* __restrict__ gcur,
    int* __restrict__ bkey, int2* __restrict__ bpay, int E, int nbuk) {
  __shared__ int hc[NBUK_MAX];
  int tid = threadIdx.x;
  int c0 = blockIdx.x * 8192;
  int c1 = min(c0 + 8192, E);
  for (int i = tid; i < nbuk; i += 256) hc[i] = 0;
  __syncthreads();
  for (int e = c0 + tid; e < c1; e += 256)
    atomicAdd(&hc[key[e] >> 6], 1);
  __syncthreads();
  for (int i = tid; i < nbuk; i += 256) {
    int c = hc[i];
    if (c) hc[i] = atomicAdd(&gcur[i], c);   // hc becomes this block's base cursor
  }
  __syncthreads();
  for (int e = c0 + tid; e < c1; e += 256) {
    int k = key[e];
    int pos = atomicAdd(&hc[k >> 6], 1);
    bkey[pos] = k;
    bpay[pos] = dsts ? make_int2(dsts[e], __float_as_int(vals[e]))
                     : make_int2(e, 0);
  }
}

// pass 2: one block per bucket (64-key sub-range). Streams bucket from global
// twice (L2-hot). Writes final payload contiguously + offs[] for its keys.
template <int PERM>
__global__ __launch_bounds__(256) void k_p2(
    const int* __restrict__ bkey, const int2* __restrict__ bpay,
    const int* __restrict__ bstart, int* __restrict__ offs,
    int* __restrict__ perm, int2* __restrict__ payF, int N, int E) {
  __shared__ int cnt[64], scn[64], cur[64];
  int b = blockIdx.x;
  int tid = threadIdx.x;
  int s = bstart[b], t = bstart[b + 1];
  if (tid < 64) cnt[tid] = 0;
  __syncthreads();
  for (int i = s + tid; i < t; i += 256) atomicAdd(&cnt[bkey[i] & 63], 1);
  __syncthreads();
  if (tid < 64) scn[tid] = cnt[tid];
  __syncthreads();
  for (int off = 1; off < 64; off <<= 1) {
    int v = 0;
    if (tid < 64 && tid >= off) v = scn[tid - off];
    __syncthreads();
    if (tid < 64 && tid >= off) scn[tid] += v;
    __syncthreads();
  }
  if (tid < 64) {
    int excl = s + scn[tid] - cnt[tid];
    cur[tid] = excl;
    int node = b * 64 + tid;
    if (node < N) offs[node] = excl;
  }
  if (b == 0 && tid == 0) offs[N] = E;
  __syncthreads();
  for (int i = s + tid; i < t; i += 256) {
    int2 p = bpay[i];
    int k = bkey[i] & 63;
    int pos = atomicAdd(&cur[k], 1);
    if (PERM) perm[pos] = p.x;
    else      payF[pos] = p;
  }
}

// rs[n] = sum of adj_value over node n's segment (for folded bias)
__global__ __launch_bounds__(256) void k_rowsum(
    const int* __restrict__ offs, const int2* __restrict__ pay,
    float* __restrict__ rs, int N) {
  int n = blockIdx.x * 256 + threadIdx.x;
  if (n >= N) return;
  int s = offs[n], t = offs[n + 1];
  float a = 0.f;
  for (int i = s; i < t; i++) a += __int_as_float(pay[i].y);
  rs[n] = a;
}

// ============================ embed stage ============================
__global__ __launch_bounds__(256) void k_embed_gather(
    const float* __restrict__ edge_attr, const int* __restrict__ offs,
    const int* __restrict__ perm, float* __restrict__ agg8, int N) {
  int n = blockIdx.x * 32 + (threadIdx.x >> 3);
  if (n >= N) return;
  int c = threadIdx.x & 7;
  int s = offs[n], t = offs[n + 1];
  float acc = 0.f;
  for (int i = s; i < t; i++) {
    int e = perm[i];
    acc += edge_attr[(size_t)e * FE + c];
  }
  agg8[(size_t)n * FE + c] = acc;
}

__global__ __launch_bounds__(256) void k_embed_h(
    const float* __restrict__ node_attr, const float* __restrict__ Wn,
    const float* __restrict__ We8, const float* __restrict__ b,
    const float* __restrict__ agg8, float* __restrict__ h, int N) {
  __shared__ float Ws[FN * H];
  __shared__ float Es[FE * H];
  __shared__ float na[2][FN];
  __shared__ float a8[2][FE];
  for (int i = threadIdx.x; i < FN * H; i += 256) Ws[i] = Wn[i];
  for (int i = threadIdx.x; i < FE * H; i += 256) Es[i] = We8[i];
  int lane = threadIdx.x & 127;
  int sub  = threadIdx.x >> 7;
  for (int n0 = blockIdx.x * 2; n0 < N; n0 += gridDim.x * 2) {
    int n = n0 + sub;
    __syncthreads();
    if (n < N) {
      if (lane < FN) na[sub][lane] = node_attr[(size_t)n * FN + lane];
      else if (lane < FN + FE) a8[sub][lane - FN] = agg8[(size_t)n * FE + (lane - FN)];
    }
    __syncthreads();
    if (n < N) {
      float acc = b[lane];
#pragma unroll
      for (int k = 0; k < FN; k++) acc += na[sub][k] * Ws[k * H + lane];
#pragma unroll
      for (int k = 0; k < FE; k++) acc += a8[sub][k] * Es[k * H + lane];
      h[(size_t)n * H + lane] = fmaxf(acc, 0.f);
    }
  }
}

// ============================ fused GCN layer ============================
// out[n] = relu( (sum_e val_e * h[dst_e]) @ W + rs[n]*b )
// Phase 1: gather-aggregate 32 nodes into LDS. Phase 2: 32x128 @ 128x128 GEMM.
__global__ __launch_bounds__(256) void k_layer(
    const float* __restrict__ h, const int* __restrict__ offs,
    const int2* __restrict__ pay, const float* __restrict__ W,
    const float* __restrict__ bias, const float* __restrict__ rs,
    float* __restrict__ out, int N) {
  __shared__ float ts[32 * H];   // 16 KB aggregated rows
  __shared__ float Ws[32 * H];   // 16 KB W k-chunk
  int tid = threadIdx.x;
  int c = tid & 31;
  int grp = tid >> 5;
  int base = blockIdx.x * 32;
  float4* ts4 = (float4*)ts;
  float4* Ws4 = (float4*)Ws;

  // ---- phase 1: each 32-lane group aggregates 4 nodes ----
#pragma unroll
  for (int r = 0; r < 4; r++) {
    int n = base + grp * 4 + r;
    float4 acc = make_float4(0.f, 0.f, 0.f, 0.f);
    if (n < N) {
      int s = offs[n], t = offs[n + 1];
      for (int i = s; i < t; i++) {
        int2 p = pay[i];
        float v = __int_as_float(p.y);
        float4 hv = ((const float4*)h)[(size_t)p.x * 32 + c];
        acc.x += v * hv.x; acc.y += v * hv.y;
        acc.z += v * hv.z; acc.w += v * hv.w;
      }
    }
    ts4[(grp * 4 + r) * 32 + c] = acc;
  }
  __syncthreads();

  // ---- phase 2: t @ W, thread = 4 rows (grp+8i) x 4 cols (c*4..) ----
  float4 a4[4];
#pragma unroll
  for (int i = 0; i < 4; i++) a4[i] = make_float4(0.f, 0.f, 0.f, 0.f);
  for (int kk = 0; kk < 4; kk++) {
    const float4* Wg = (const float4*)(W + (size_t)kk * 32 * H);
#pragma unroll
    for (int p = 0; p < 4; p++) Ws4[tid + 256 * p] = Wg[tid + 256 * p];
    __syncthreads();
#pragma unroll
    for (int k4 = 0; k4 < 8; k4++) {
      float4 w0 = Ws4[(k4 * 4 + 0) * 32 + c];
      float4 w1 = Ws4[(k4 * 4 + 1) * 32 + c];
      float4 w2 = Ws4[(k4 * 4 + 2) * 32 + c];
      float4 w3 = Ws4[(k4 * 4 + 3) * 32 + c];
#pragma unroll
      for (int i = 0; i < 4; i++) {
        float4 hv = ts4[(grp + 8 * i) * 32 + kk * 8 + k4];
        a4[i].x += hv.x * w0.x + hv.y * w1.x + hv.z * w2.x + hv.w * w3.x;
        a4[i].y += hv.x * w0.y + hv.y * w1.y + hv.z * w2.y + hv.w * w3.y;
        a4[i].z += hv.x * w0.z + hv.y * w1.z + hv.z * w2.z + hv.w * w3.z;
        a4[i].w += hv.x * w0.w + hv.y * w1.w + hv.z * w2.w + hv.w * w3.w;
      }
    }
    __syncthreads();
  }
  float4 bv = ((const float4*)bias)[c];
#pragma unroll
  for (int i = 0; i < 4; i++) {
    int n = base + grp + 8 * i;
    if (n < N) {
      float r = rs[n];
      float4 o;
      o.x = fmaxf(a4[i].x + r * bv.x, 0.f);
      o.y = fmaxf(a4[i].y + r * bv.y, 0.f);
      o.z = fmaxf(a4[i].z + r * bv.z, 0.f);
      o.w = fmaxf(a4[i].w + r * bv.w, 0.f);
      ((float4*)(out + (size_t)n * H))[c] = o;
    }
  }
}

// ============================ pool + predictor ============================
__global__ __launch_bounds__(256) void k_gbounds(
    const int* __restrict__ batch, int* __restrict__ gstart, int N, int G) {
  int n = blockIdx.x * 256 + threadIdx.x;
  if (n > N) return;
  if (n == 0) {
    for (int g = 0; g <= batch[0]; g++) gstart[g] = 0;
  } else if (n == N) {
    for (int g = batch[N - 1] + 1; g <= G; g++) gstart[g] = N;
  } else {
    int b0 = batch[n - 1], b1 = batch[n];
    for (int g = b0 + 1; g <= b1; g++) gstart[g] = n;
  }
}

__global__ __launch_bounds__(128) void k_pool_seg(
    const float* __restrict__ h, const int* __restrict__ gstart,
    float* __restrict__ fp, int G) {
  int g = blockIdx.x;
  int j = threadIdx.x;
  int s = gstart[g], t = gstart[g + 1];
  float acc = 0.f;
  for (int n = s; n < t; n++) acc += h[(size_t)n * H + j];
  fp[(size_t)g * H + j] = acc;
}

__global__ __launch_bounds__(128) void k_pred(
    const float* __restrict__ fp, const float* __restrict__ Wp1,
    const float* __restrict__ bp1, const float* __restrict__ Wp2,
    const float* __restrict__ bp2, float* __restrict__ out, int G) {
  __shared__ float fs[H];
  __shared__ float partial[2];
  int g = blockIdx.x;
  int j = threadIdx.x;
  fs[j] = fp[(size_t)g * H + j];
  __syncthreads();
  float acc = bp1[j];
#pragma unroll 4
  for (int k = 0; k < H; k++) acc += fs[k] * Wp1[(size_t)k * H + j];
  float z = fmaxf(acc, 0.f) * Wp2[j];
#pragma unroll
  for (int off = 32; off > 0; off >>= 1) z += __shfl_down(z, off, 64);
  if ((j & 63) == 0) partial[j >> 6] = z;
  __syncthreads();
  if (j == 0) out[g] = partial[0] + partial[1] + bp2[0];
}

// ============================ launch ============================
extern "C" void kernel_launch(void* const* d_in, const int* in_sizes, int n_in,
                              void* d_out, int out_size, void* d_ws, size_t ws_size,
                              hipStream_t stream) {
  const float* node_attr  = (const float*)d_in[0];
  const float* edge_attr  = (const float*)d_in[1];
  const int*   edge_index = (const int*)d_in[2];
  const int*   adj_index  = (const int*)d_in[3];
  const float* adj_value  = (const float*)d_in[4];
  const int*   batch      = (const int*)d_in[5];
  const float* W_node  = (const float*)d_in[6];
  const float* W_edge  = (const float*)d_in[7];
  const float* b_embed = (const float*)d_in[8];
  const float* W1 = (const float*)d_in[9];
  const float* b1 = (const float*)d_in[10];
  const float* W2 = (const float*)d_in[11];
  const float* b2 = (const float*)d_in[12];
  const float* W3 = (const float*)d_in[13];
  const float* b3 = (const float*)d_in[14];
  const float* Wp1 = (const float*)d_in[15];
  const float* bp1 = (const float*)d_in[16];
  const float* Wp2 = (const float*)d_in[17];
  const float* bp2 = (const float*)d_in[18];
  float* out = (float*)d_out;

  const int E = in_sizes[4];           // 1,600,000
  const int N = in_sizes[5];           // 100,000
  const int G = out_size;              // 2048
  const int nbuk = (N + 63) >> 6;      // 1563
  const int NBS = (nbuk + 1023) / 1024;
  const int p1b = (E + 8191) / 8192;

  // ---- workspace layout (~117 MB) ----
  float* A     = (float*)d_ws;                       // N*H (51.2 MB)
  float* B     = A + (size_t)N * H;                  // N*H (51.2 MB)
  int2*  payF  = (int2*)(B + (size_t)N * H);         // E   (12.8 MB)
  float* fpool = (float*)(payF + E);                 // G*H
  int*   offs1 = (int*)(fpool + (size_t)G * H);      // N+1
  int*   offs2 = offs1 + (N + 1);                    // N+1
  float* rs    = (float*)(offs2 + (N + 1));          // N
  int*   bcnt  = (int*)(rs + N);                     // nbuk
  int*   bstart= bcnt + nbuk;                        // nbuk+1
  int*   gcur  = bstart + nbuk + 1;                  // nbuk
  int*   bsum  = gcur + nbuk;                        // 128
  int*   bsumEx= bsum + 128;                         // 128
  int*   gstart= bsumEx + 128;                       // G+1
  // transient aliases (lifetimes verified by launch order):
  int*   perm  = (int*)A;                            // E ints, dead before layer1 writes A
  float* agg8  = A + 2000000;                        // N*FE, past perm, dead before layer1
  int*   bkey  = (int*)B;                            // E ints, dead before embed_h writes B
  int2*  bpay  = (int2*)(((int*)B) + E);             // E int2

  // ---- sort 1: edges by dst -> perm + offs1 ----
  hipMemsetAsync(bcnt, 0, (size_t)nbuk * sizeof(int), stream);
  k_p1_hist<<<256, 256, 0, stream>>>(edge_index + E, bcnt, E, nbuk);
  k_scan1<<<NBS, 256, 0, stream>>>(bcnt, bsum, nbuk);
  k_scan2<<<1, 128, 0, stream>>>(bsum, bsumEx, bstart, NBS, nbuk);
  k_scan3<<<NBS, 256, 0, stream>>>(bcnt, bsumEx, bstart, nbuk);
  hipMemcpyAsync(gcur, bstart, (size_t)nbuk * sizeof(int), hipMemcpyDeviceToDevice, stream);
  k_p1_scatter<<<p1b, 256, 0, stream>>>(edge_index + E, nullptr, nullptr,
                                        gcur, bkey, bpay, E, nbuk);
  k_p2<1><<<nbuk, 256, 0, stream>>>(bkey, bpay, bstart, offs1, perm, nullptr, N, E);

  // ---- sort 2: adj by src, payload (dst,val) -> payF + offs2 ----
  hipMemsetAsync(bcnt, 0, (size_t)nbuk * sizeof(int), stream);
  k_p1_hist<<<256, 256, 0, stream>>>(adj_index, bcnt, E, nbuk);
  k_scan1<<<NBS, 256, 0, stream>>>(bcnt, bsum, nbuk);
  k_scan2<<<1, 128, 0, stream>>>(bsum, bsumEx, bstart, NBS, nbuk);
  k_scan3<<<NBS, 256, 0, stream>>>(bcnt, bsumEx, bstart, nbuk);
  hipMemcpyAsync(gcur, bstart, (size_t)nbuk * sizeof(int), hipMemcpyDeviceToDevice, stream);
  k_p1_scatter<<<p1b, 256, 0, stream>>>(adj_index, adj_index + E, adj_value,
                                        gcur, bkey, bpay, E, nbuk);
  k_p2<0><<<nbuk, 256, 0, stream>>>(bkey, bpay, bstart, offs2, nullptr, payF, N, E);
  k_rowsum<<<(N + 255) / 256, 256, 0, stream>>>(offs2, payF, rs, N);

  // ---- embed (after sorts: bkey/bpay in B-region now dead) ----
  k_embed_gather<<<(N + 31) / 32, 256, 0, stream>>>(edge_attr, offs1, perm, agg8, N);
  k_embed_h<<<4096, 256, 0, stream>>>(node_attr, W_node, W_edge, b_embed, agg8, B, N);

  k_gbounds<<<(N + 256) / 256, 256, 0, stream>>>(batch, gstart, N, G);

  // ---- 3 fused GCN layers ----
  int lb = (N + 31) / 32;
  k_layer<<<lb, 256, 0, stream>>>(B, offs2, payF, W1, b1, rs, A, N);
  k_layer<<<lb, 256, 0, stream>>>(A, offs2, payF, W2, b2, rs, B, N);
  k_layer<<<lb, 256, 0, stream>>>(B, offs2, payF, W3, b3, rs, A, N);

  // ---- pool + predictor ----
  k_pool_seg<<<G, 128, 0, stream>>>(A, gstart, fpool, G);
  k_pred<<<G, 128, 0, stream>>>(fpool, Wp1, bp1, Wp2, bp2, out, G);
}

// Round 4
// 1145.756 us; speedup vs baseline: 1.3126x; 1.3126x over previous
//
#include <hip/hip_runtime.h>

#define H 128
#define FN 16
#define FE 8
#define NBUK_MAX 1600   // buckets = ceil(N/64) = 1563 for N=100k

// ============================ bucketed counting sort ============================
// Pass 1: bin edges by key>>6 into contiguous bucket regions (coalesced writes).
// Pass 2: per-bucket counting sort over the 64-key sub-range; emits offs[].

__global__ __launch_bounds__(256) void k_p1_hist(
    const int* __restrict__ key, int* __restrict__ bcnt, int E, int nbuk) {
  __shared__ int h[NBUK_MAX];
  for (int i = threadIdx.x; i < nbuk; i += 256) h[i] = 0;
  __syncthreads();
  for (int e = blockIdx.x * 256 + threadIdx.x; e < E; e += gridDim.x * 256)
    atomicAdd(&h[key[e] >> 6], 1);
  __syncthreads();
  for (int i = threadIdx.x; i < nbuk; i += 256) {
    int v = h[i];
    if (v) atomicAdd(&bcnt[i], v);
  }
}

__global__ __launch_bounds__(256) void k_scan1(
    const int* __restrict__ cnt, int* __restrict__ bsum, int N) {
  __shared__ int s[256];
  int base = blockIdx.x * 1024 + threadIdx.x * 4;
  int t = 0;
#pragma unroll
  for (int j = 0; j < 4; j++) { int i = base + j; if (i < N) t += cnt[i]; }
  s[threadIdx.x] = t; __syncthreads();
  for (int off = 128; off > 0; off >>= 1) {
    if (threadIdx.x < off) s[threadIdx.x] += s[threadIdx.x + off];
    __syncthreads();
  }
  if (threadIdx.x == 0) bsum[blockIdx.x] = s[0];
}

__global__ __launch_bounds__(128) void k_scan2(
    const int* __restrict__ bsum, int* __restrict__ bsumEx,
    int* __restrict__ offs, int NB, int N) {
  __shared__ int s[128];
  int tid = threadIdx.x;
  int v = (tid < NB) ? bsum[tid] : 0;
  s[tid] = v; __syncthreads();
  for (int off = 1; off < 128; off <<= 1) {
    int t = 0;
    if (tid >= off) t = s[tid - off];
    __syncthreads();
    if (tid >= off) s[tid] += t;
    __syncthreads();
  }
  if (tid < NB) bsumEx[tid] = s[tid] - v;
  if (tid == 127) offs[N] = s[127];
}

__global__ __launch_bounds__(256) void k_scan3(
    const int* __restrict__ cnt, const int* __restrict__ bsumEx,
    int* __restrict__ offs, int N) {
  __shared__ int s[256];
  int tid = threadIdx.x;
  int base = blockIdx.x * 1024 + tid * 4;
  int c[4]; int t = 0;
#pragma unroll
  for (int j = 0; j < 4; j++) { int i = base + j; c[j] = (i < N) ? cnt[i] : 0; t += c[j]; }
  s[tid] = t; __syncthreads();
  for (int off = 1; off < 256; off <<= 1) {
    int u = 0;
    if (tid >= off) u = s[tid - off];
    __syncthreads();
    if (tid >= off) s[tid] += u;
    __syncthreads();
  }
  int ex = s[tid] - t + bsumEx[blockIdx.x];
#pragma unroll
  for (int j = 0; j < 4; j++) {
    int i = base + j;
    if (i < N) offs[i] = ex;
    ex += c[j];
  }
}

__global__ __launch_bounds__(256) void k_p1_scatter(
    const int* __restrict__ key, const int* __restrict__ dsts,
    const float* __restrict__ vals, int* __restrict__ gcur,
    int* __restrict__ bkey, int2* __restrict__ bpay, int E, int nbuk) {
  __shared__ int hc[NBUK_MAX];
  int tid = threadIdx.x;
  int c0 = blockIdx.x * 8192;
  int c1 = min(c0 + 8192, E);
  for (int i = tid; i < nbuk; i += 256) hc[i] = 0;
  __syncthreads();
  for (int e = c0 + tid; e < c1; e += 256)
    atomicAdd(&hc[key[e] >> 6], 1);
  __syncthreads();
  for (int i = tid; i < nbuk; i += 256) {
    int c = hc[i];
    if (c) hc[i] = atomicAdd(&gcur[i], c);
  }
  __syncthreads();
  for (int e = c0 + tid; e < c1; e += 256) {
    int k = key[e];
    int pos = atomicAdd(&hc[k >> 6], 1);
    bkey[pos] = k;
    bpay[pos] = dsts ? make_int2(dsts[e], __float_as_int(vals[e]))
                     : make_int2(e, 0);
  }
}

template <int PERM>
__global__ __launch_bounds__(256) void k_p2(
    const int* __restrict__ bkey, const int2* __restrict__ bpay,
    const int* __restrict__ bstart, int* __restrict__ offs,
    int* __restrict__ perm, int2* __restrict__ payF, int N, int E) {
  __shared__ int cnt[64], scn[64], cur[64];
  int b = blockIdx.x;
  int tid = threadIdx.x;
  int s = bstart[b], t = bstart[b + 1];
  if (tid < 64) cnt[tid] = 0;
  __syncthreads();
  for (int i = s + tid; i < t; i += 256) atomicAdd(&cnt[bkey[i] & 63], 1);
  __syncthreads();
  if (tid < 64) scn[tid] = cnt[tid];
  __syncthreads();
  for (int off = 1; off < 64; off <<= 1) {
    int v = 0;
    if (tid < 64 && tid >= off) v = scn[tid - off];
    __syncthreads();
    if (tid < 64 && tid >= off) scn[tid] += v;
    __syncthreads();
  }
  if (tid < 64) {
    int excl = s + scn[tid] - cnt[tid];
    cur[tid] = excl;
    int node = b * 64 + tid;
    if (node < N) offs[node] = excl;
  }
  if (b == 0 && tid == 0) offs[N] = E;
  __syncthreads();
  for (int i = s + tid; i < t; i += 256) {
    int2 p = bpay[i];
    int k = bkey[i] & 63;
    int pos = atomicAdd(&cur[k], 1);
    if (PERM) perm[pos] = p.x;
    else      payF[pos] = p;
  }
}

// ============================ embed stage ============================
__global__ __launch_bounds__(256) void k_embed_gather(
    const float* __restrict__ edge_attr, const int* __restrict__ offs,
    const int* __restrict__ perm, float* __restrict__ agg8, int N) {
  int n = blockIdx.x * 32 + (threadIdx.x >> 3);
  if (n >= N) return;
  int c = threadIdx.x & 7;
  int s = offs[n], t = offs[n + 1];
  float acc = 0.f;
  for (int i = s; i < t; i++) {
    int e = perm[i];
    acc += edge_attr[(size_t)e * FE + c];
  }
  agg8[(size_t)n * FE + c] = acc;
}

__global__ __launch_bounds__(256) void k_embed_h(
    const float* __restrict__ node_attr, const float* __restrict__ Wn,
    const float* __restrict__ We8, const float* __restrict__ b,
    const float* __restrict__ agg8, float* __restrict__ h, int N) {
  __shared__ float Ws[FN * H];
  __shared__ float Es[FE * H];
  __shared__ float na[2][FN];
  __shared__ float a8[2][FE];
  for (int i = threadIdx.x; i < FN * H; i += 256) Ws[i] = Wn[i];
  for (int i = threadIdx.x; i < FE * H; i += 256) Es[i] = We8[i];
  int lane = threadIdx.x & 127;
  int sub  = threadIdx.x >> 7;
  for (int n0 = blockIdx.x * 2; n0 < N; n0 += gridDim.x * 2) {
    int n = n0 + sub;
    __syncthreads();
    if (n < N) {
      if (lane < FN) na[sub][lane] = node_attr[(size_t)n * FN + lane];
      else if (lane < FN + FE) a8[sub][lane - FN] = agg8[(size_t)n * FE + (lane - FN)];
    }
    __syncthreads();
    if (n < N) {
      float acc = b[lane];
#pragma unroll
      for (int k = 0; k < FN; k++) acc += na[sub][k] * Ws[k * H + lane];
#pragma unroll
      for (int k = 0; k < FE; k++) acc += a8[sub][k] * Es[k * H + lane];
      h[(size_t)n * H + lane] = fmaxf(acc, 0.f);
    }
  }
}

// ============================ dense GEMM [N,H]@[H,H]+b ============================
// 64 rows x 128 cols per block; k staged in LDS chunks of 32.
__global__ __launch_bounds__(256) void k_gemm(
    const float* __restrict__ in, const float* __restrict__ W,
    const float* __restrict__ bias, float* __restrict__ out, int N) {
  __shared__ float Ws[32 * H];   // 16 KB
  __shared__ float hs[64 * 32];  // 8 KB
  int tid = threadIdx.x;
  int c = tid & 31;
  int rg = tid >> 5;
  int rowBase = blockIdx.x * 64;
  float4 acc[8];
#pragma unroll
  for (int i = 0; i < 8; i++) acc[i] = make_float4(0.f, 0.f, 0.f, 0.f);

  float4* Ws4 = (float4*)Ws;
  float4* hs4 = (float4*)hs;
  for (int kk = 0; kk < 4; kk++) {
    const float4* Wg = (const float4*)(W + (size_t)kk * 32 * H);
#pragma unroll
    for (int p = 0; p < 4; p++) Ws4[tid + 256 * p] = Wg[tid + 256 * p];
#pragma unroll
    for (int p = 0; p < 2; p++) {
      int q = tid + 256 * p;
      int r = q >> 3, kq = q & 7;
      int row = rowBase + r;
      float4 v = make_float4(0.f, 0.f, 0.f, 0.f);
      if (row < N) v = ((const float4*)(in + (size_t)row * H + kk * 32))[kq];
      hs4[q] = v;
    }
    __syncthreads();
#pragma unroll
    for (int k4 = 0; k4 < 8; k4++) {
      float4 w0 = Ws4[(k4 * 4 + 0) * 32 + c];
      float4 w1 = Ws4[(k4 * 4 + 1) * 32 + c];
      float4 w2 = Ws4[(k4 * 4 + 2) * 32 + c];
      float4 w3 = Ws4[(k4 * 4 + 3) * 32 + c];
#pragma unroll
      for (int i = 0; i < 8; i++) {
        float4 hv = hs4[(rg + 8 * i) * 8 + k4];
        acc[i].x += hv.x * w0.x + hv.y * w1.x + hv.z * w2.x + hv.w * w3.x;
        acc[i].y += hv.x * w0.y + hv.y * w1.y + hv.z * w2.y + hv.w * w3.y;
        acc[i].z += hv.x * w0.z + hv.y * w1.z + hv.z * w2.z + hv.w * w3.z;
        acc[i].w += hv.x * w0.w + hv.y * w1.w + hv.z * w2.w + hv.w * w3.w;
      }
    }
    __syncthreads();
  }
  float4 bv = ((const float4*)bias)[c];
#pragma unroll
  for (int i = 0; i < 8; i++) {
    int row = rowBase + rg + 8 * i;
    if (row < N) {
      float4 o = make_float4(acc[i].x + bv.x, acc[i].y + bv.y,
                             acc[i].z + bv.z, acc[i].w + bv.w);
      ((float4*)(out + (size_t)row * H))[c] = o;
    }
  }
}

// ============================ GCN gather-aggregate (high occupancy) ============================
// out[n] = relu( sum_{i in seg(n)} val_i * hw[dst_i] )
__global__ __launch_bounds__(256) void k_gcn_gather(
    const float* __restrict__ hw, const int* __restrict__ offs,
    const int2* __restrict__ pay, float* __restrict__ out, int N) {
  int n = blockIdx.x * 8 + (threadIdx.x >> 5);
  if (n >= N) return;
  int c = threadIdx.x & 31;
  int s = offs[n], t = offs[n + 1];
  float4 acc = make_float4(0.f, 0.f, 0.f, 0.f);
  for (int i = s; i < t; i++) {
    int2 p = pay[i];
    float v = __int_as_float(p.y);
    float4 hv = ((const float4*)hw)[(size_t)p.x * 32 + c];
    acc.x += v * hv.x; acc.y += v * hv.y;
    acc.z += v * hv.z; acc.w += v * hv.w;
  }
  float4 o = make_float4(fmaxf(acc.x, 0.f), fmaxf(acc.y, 0.f),
                         fmaxf(acc.z, 0.f), fmaxf(acc.w, 0.f));
  ((float4*)(out + (size_t)n * H))[c] = o;
}

// ============================ pool + predictor ============================
__global__ __launch_bounds__(256) void k_gbounds(
    const int* __restrict__ batch, int* __restrict__ gstart, int N, int G) {
  int n = blockIdx.x * 256 + threadIdx.x;
  if (n > N) return;
  if (n == 0) {
    for (int g = 0; g <= batch[0]; g++) gstart[g] = 0;
  } else if (n == N) {
    for (int g = batch[N - 1] + 1; g <= G; g++) gstart[g] = N;
  } else {
    int b0 = batch[n - 1], b1 = batch[n];
    for (int g = b0 + 1; g <= b1; g++) gstart[g] = n;
  }
}

__global__ __launch_bounds__(128) void k_pool_seg(
    const float* __restrict__ h, const int* __restrict__ gstart,
    float* __restrict__ fp, int G) {
  int g = blockIdx.x;
  int j = threadIdx.x;
  int s = gstart[g], t = gstart[g + 1];
  float acc = 0.f;
  for (int n = s; n < t; n++) acc += h[(size_t)n * H + j];
  fp[(size_t)g * H + j] = acc;
}

__global__ __launch_bounds__(128) void k_pred(
    const float* __restrict__ fp, const float* __restrict__ Wp1,
    const float* __restrict__ bp1, const float* __restrict__ Wp2,
    const float* __restrict__ bp2, float* __restrict__ out, int G) {
  __shared__ float fs[H];
  __shared__ float partial[2];
  int g = blockIdx.x;
  int j = threadIdx.x;
  fs[j] = fp[(size_t)g * H + j];
  __syncthreads();
  float acc = bp1[j];
#pragma unroll 4
  for (int k = 0; k < H; k++) acc += fs[k] * Wp1[(size_t)k * H + j];
  float z = fmaxf(acc, 0.f) * Wp2[j];
#pragma unroll
  for (int off = 32; off > 0; off >>= 1) z += __shfl_down(z, off, 64);
  if ((j & 63) == 0) partial[j >> 6] = z;
  __syncthreads();
  if (j == 0) out[g] = partial[0] + partial[1] + bp2[0];
}

// ============================ launch ============================
extern "C" void kernel_launch(void* const* d_in, const int* in_sizes, int n_in,
                              void* d_out, int out_size, void* d_ws, size_t ws_size,
                              hipStream_t stream) {
  const float* node_attr  = (const float*)d_in[0];
  const float* edge_attr  = (const float*)d_in[1];
  const int*   edge_index = (const int*)d_in[2];
  const int*   adj_index  = (const int*)d_in[3];
  const float* adj_value  = (const float*)d_in[4];
  const int*   batch      = (const int*)d_in[5];
  const float* W_node  = (const float*)d_in[6];
  const float* W_edge  = (const float*)d_in[7];
  const float* b_embed = (const float*)d_in[8];
  const float* W1 = (const float*)d_in[9];
  const float* b1 = (const float*)d_in[10];
  const float* W2 = (const float*)d_in[11];
  const float* b2 = (const float*)d_in[12];
  const float* W3 = (const float*)d_in[13];
  const float* b3 = (const float*)d_in[14];
  const float* Wp1 = (const float*)d_in[15];
  const float* bp1 = (const float*)d_in[16];
  const float* Wp2 = (const float*)d_in[17];
  const float* bp2 = (const float*)d_in[18];
  float* out = (float*)d_out;

  const int E = in_sizes[4];           // 1,600,000
  const int N = in_sizes[5];           // 100,000
  const int G = out_size;              // 2048
  const int nbuk = (N + 63) >> 6;      // 1563
  const int NBS = (nbuk + 1023) / 1024;
  const int p1b = (E + 8191) / 8192;

  // ---- workspace layout ----
  float* A     = (float*)d_ws;                       // N*H (51.2 MB)
  float* B     = A + (size_t)N * H;                  // N*H (51.2 MB)
  int2*  payF  = (int2*)(B + (size_t)N * H);         // E   (12.8 MB)
  float* fpool = (float*)(payF + E);                 // G*H
  int*   offs1 = (int*)(fpool + (size_t)G * H);      // N+1
  int*   offs2 = offs1 + (N + 1);                    // N+1
  int*   bcnt  = offs2 + (N + 1);                    // nbuk
  int*   bstart= bcnt + nbuk;                        // nbuk+1
  int*   gcur  = bstart + nbuk + 1;                  // nbuk
  int*   bsum  = gcur + nbuk;                        // 128
  int*   bsumEx= bsum + 128;                         // 128
  int*   gstart= bsumEx + 128;                       // G+1
  // transient aliases (dead before their region is overwritten):
  int*   perm  = (int*)A;                            // E ints; dead after embed_gather
  float* agg8  = A + 2000000;                        // N*FE; dead after embed_h
  int*   bkey  = (int*)B;                            // E ints; dead before embed_h writes B
  int2*  bpay  = (int2*)(((int*)B) + E);             // E int2

  // ---- sort 1: edges by dst -> perm + offs1 ----
  hipMemsetAsync(bcnt, 0, (size_t)nbuk * sizeof(int), stream);
  k_p1_hist<<<256, 256, 0, stream>>>(edge_index + E, bcnt, E, nbuk);
  k_scan1<<<NBS, 256, 0, stream>>>(bcnt, bsum, nbuk);
  k_scan2<<<1, 128, 0, stream>>>(bsum, bsumEx, bstart, NBS, nbuk);
  k_scan3<<<NBS, 256, 0, stream>>>(bcnt, bsumEx, bstart, nbuk);
  hipMemcpyAsync(gcur, bstart, (size_t)nbuk * sizeof(int), hipMemcpyDeviceToDevice, stream);
  k_p1_scatter<<<p1b, 256, 0, stream>>>(edge_index + E, nullptr, nullptr,
                                        gcur, bkey, bpay, E, nbuk);
  k_p2<1><<<nbuk, 256, 0, stream>>>(bkey, bpay, bstart, offs1, perm, nullptr, N, E);

  // ---- sort 2: adj by src, payload (dst,val) -> payF + offs2 ----
  hipMemsetAsync(bcnt, 0, (size_t)nbuk * sizeof(int), stream);
  k_p1_hist<<<256, 256, 0, stream>>>(adj_index, bcnt, E, nbuk);
  k_scan1<<<NBS, 256, 0, stream>>>(bcnt, bsum, nbuk);
  k_scan2<<<1, 128, 0, stream>>>(bsum, bsumEx, bstart, NBS, nbuk);
  k_scan3<<<NBS, 256, 0, stream>>>(bcnt, bsumEx, bstart, nbuk);
  hipMemcpyAsync(gcur, bstart, (size_t)nbuk * sizeof(int), hipMemcpyDeviceToDevice, stream);
  k_p1_scatter<<<p1b, 256, 0, stream>>>(adj_index, adj_index + E, adj_value,
                                        gcur, bkey, bpay, E, nbuk);
  k_p2<0><<<nbuk, 256, 0, stream>>>(bkey, bpay, bstart, offs2, nullptr, payF, N, E);

  // ---- embed (bkey/bpay in B-region dead after sorts) ----
  k_embed_gather<<<(N + 31) / 32, 256, 0, stream>>>(edge_attr, offs1, perm, agg8, N);
  k_embed_h<<<4096, 256, 0, stream>>>(node_attr, W_node, W_edge, b_embed, agg8, B, N);

  k_gbounds<<<(N + 256) / 256, 256, 0, stream>>>(batch, gstart, N, G);

  // ---- 3 GCN layers: A = B@W+b ; B = relu(gather(A)) ----
  int gemm_blocks = (N + 63) / 64;
  int agb = (N + 7) / 8;
  k_gemm<<<gemm_blocks, 256, 0, stream>>>(B, W1, b1, A, N);
  k_gcn_gather<<<agb, 256, 0, stream>>>(A, offs2, payF, B, N);
  k_gemm<<<gemm_blocks, 256, 0, stream>>>(B, W2, b2, A, N);
  k_gcn_gather<<<agb, 256, 0, stream>>>(A, offs2, payF, B, N);
  k_gemm<<<gemm_blocks, 256, 0, stream>>>(B, W3, b3, A, N);
  k_gcn_gather<<<agb, 256, 0, stream>>>(A, offs2, payF, B, N);

  // ---- pool + predictor ----
  k_pool_seg<<<G, 128, 0, stream>>>(B, gstart, fpool, G);
  k_pred<<<G, 128, 0, stream>>>(fpool, Wp1, bp1, Wp2, bp2, out, G);
}